// Round 5
// baseline (352.094 us; speedup 1.0000x reference)
//
#include <hip/hip_runtime.h>
#include <hip/hip_bf16.h>
#include <stdint.h>

#define NN 100000
#define NE 1600000
#define NR (NE + NN)   // records incl. self-loops
#define DD 128
#define NEG 0.01f
#define NB 196        // coarse buckets of 512 nodes (dst>>9)
#define EPB 4096      // edges per block in hist/scatter
#define NBLK1 391     // ceil(NE/EPB)

typedef __attribute__((ext_vector_type(8))) short short8;
typedef __attribute__((ext_vector_type(4))) float floatx4;
typedef __attribute__((ext_vector_type(4))) uint32_t uint32x4;

__device__ __forceinline__ uint16_t f2bf(float f){
  uint32_t i = __float_as_uint(f);
  return (uint16_t)((i + 0x7FFFu + ((i >> 16) & 1u)) >> 16);  // RNE
}
__device__ __forceinline__ float lrelu(float x){ return fmaxf(x, NEG * x); }

// ---------------- dtype detect: are float tensors f32 or bf16? ----------------
__global__ void k_detect(const uint32_t* __restrict__ xw, int* __restrict__ flag){
  int lane = threadIdx.x;
  uint32_t w = xw[lane];
  uint32_t e = (w >> 7) & 0xFFu;
  int plaus = (e >= 100u && e <= 134u) ? 1 : 0;
  unsigned long long b = __ballot(plaus);
  if (lane == 0) flag[0] = (__popcll(b) >= 48) ? 0 : 1;
}

// ---------------- CSR build: deterministic two-level counting sort ------------
__global__ __launch_bounds__(256) void k_hist(const int* __restrict__ dst,
                                              int* __restrict__ ghist){
  __shared__ int lh[NB];
  int t = threadIdx.x, b = blockIdx.x;
  if (t < NB) lh[t] = 0;
  __syncthreads();
  #pragma unroll
  for (int i = 0; i < 16; i++){
    int e = b * EPB + i * 256 + t;
    if (e < NE) atomicAdd(&lh[dst[e] >> 9], 1);
  }
  __syncthreads();
  if (t < NB) ghist[t * NBLK1 + b] = lh[t];
}

__global__ __launch_bounds__(512) void k_bscan(int* __restrict__ ghist,
                                               int* __restrict__ btotal){
  __shared__ int sm[512];
  int t = threadIdx.x, bkt = blockIdx.x;
  int v = (t < NBLK1) ? ghist[bkt * NBLK1 + t] : 0;
  sm[t] = v;
  __syncthreads();
  for (int s = 1; s < 512; s <<= 1){
    int add = (t >= s) ? sm[t - s] : 0;
    __syncthreads();
    sm[t] += add;
    __syncthreads();
  }
  if (t < NBLK1) ghist[bkt * NBLK1 + t] = sm[t] - v;   // exclusive
  if (t == 0) btotal[bkt] = sm[511];
}

__global__ __launch_bounds__(256) void k_bscan2(const int* __restrict__ btotal,
                                                int* __restrict__ bucketbase){
  __shared__ int sm[256];
  int t = threadIdx.x;
  int v = (t < NB) ? btotal[t] : 0;
  sm[t] = v;
  __syncthreads();
  for (int s = 1; s < 256; s <<= 1){
    int add = (t >= s) ? sm[t - s] : 0;
    __syncthreads();
    sm[t] += add;
    __syncthreads();
  }
  if (t < NB) bucketbase[t] = sm[t] - v;
  if (t == 0) bucketbase[NB] = sm[255];   // == NE
}

__global__ __launch_bounds__(256) void k_scatter(const int* __restrict__ src,
                                                 const int* __restrict__ dst,
                                                 const int* __restrict__ ghist,
                                                 const int* __restrict__ bucketbase,
                                                 uint64_t* __restrict__ pairs){
  __shared__ int lcur[NB];
  int t = threadIdx.x, b = blockIdx.x;
  if (t < NB) lcur[t] = bucketbase[t] + ghist[t * NBLK1 + b];
  __syncthreads();
  #pragma unroll
  for (int i = 0; i < 16; i++){
    int e = b * EPB + i * 256 + t;
    if (e < NE){
      int s = src[e], d = dst[e];
      int pos = atomicAdd(&lcur[d >> 9], 1);
      pairs[pos] = ((uint64_t)(uint32_t)d << 32) | (uint32_t)s;
    }
  }
}

// Per-bucket fine sort -> record stream pairs2 {src, partial coef}, prowstart, dis.
// Records per node: [self {n, dn}] then [edges {src, dn}]; k_prep2 multiplies
// every record's coef by dis[src] afterwards (self becomes dn^2).
__global__ __launch_bounds__(512) void k_bsort(const uint64_t* __restrict__ pairs,
                                               const int* __restrict__ bucketbase,
                                               int2* __restrict__ pairs2,
                                               int* __restrict__ prowstart,
                                               float* __restrict__ dis){
  __shared__ int lcnt[512], lofs[512], sm[512];
  __shared__ float sdn[512];
  int t = threadIdx.x, bkt = blockIdx.x;
  int n0 = bkt << 9;
  int beg = bucketbase[bkt], end = bucketbase[bkt + 1];
  int begS = beg + n0;                   // self-inclusive base (n0 nodes precede)
  lcnt[t] = 0;
  __syncthreads();
  for (int i = beg + t; i < end; i += 512){
    int d = (int)(pairs[i] >> 32);
    atomicAdd(&lcnt[d - n0], 1);
  }
  __syncthreads();
  int n = n0 + t;
  int inb = (n < NN) ? 1 : 0;
  int v = lcnt[t] + inb;                 // +1 slot for self record
  sm[t] = v;
  __syncthreads();
  for (int s = 1; s < 512; s <<= 1){
    int add = (t >= s) ? sm[t - s] : 0;
    __syncthreads();
    sm[t] += add;
    __syncthreads();
  }
  int excl = sm[t] - v;
  float dn = rsqrtf((float)(lcnt[t] + 1));
  lofs[t] = excl + 1;                    // first edge slot (after self)
  sdn[t] = dn;
  if (inb){
    prowstart[n] = begS + excl;
    dis[n] = dn;
    pairs2[begS + excl] = make_int2(n, __float_as_int(dn));   // partial self
  }
  if (bkt == 0 && t == 0) prowstart[NN] = NR;
  __syncthreads();
  for (int i = beg + t; i < end; i += 512){
    uint64_t u = pairs[i];
    int d = (int)(u >> 32);
    int p = atomicAdd(&lofs[d - n0], 1);
    pairs2[begS + p] = make_int2((int)(uint32_t)u, __float_as_int(sdn[d - n0]));
  }
}

// Finalize coefs: rec.coef *= dis[rec.src]  (edge-parallel, coalesced)
__global__ void k_prep2(int2* __restrict__ pairs2, const float* __restrict__ dis){
  int i = blockIdx.x * 256 + threadIdx.x;
  if (i < NR){
    int2 r = pairs2[i];
    r.y = __float_as_int(__int_as_float(r.y) * dis[r.x]);
    pairs2[i] = r;
  }
}

// ---------------- weights transpose + bias pack (merged, +dtype convert) ------
__global__ void k_wb(const void* __restrict__ W1, const void* __restrict__ W2,
                     const void* __restrict__ b1, const void* __restrict__ b2,
                     uint16_t* __restrict__ WT1, uint16_t* __restrict__ WT2,
                     uint16_t* __restrict__ bb, const int* __restrict__ flag){
  int idx = blockIdx.x * 256 + threadIdx.x;   // 129 blocks -> 33024
  int f = flag[0];
  if (idx < 16384){
    int c = idx >> 7, k = idx & 127;
    WT1[idx] = f ? f2bf(((const float*)W1)[k * DD + c])
                 : ((const uint16_t*)W1)[k * DD + c];
  } else if (idx < 32768){
    int j = idx - 16384;
    int c = j >> 7, k = j & 127;
    WT2[j] = f ? f2bf(((const float*)W2)[k * DD + c])
               : ((const uint16_t*)W2)[k * DD + c];
  } else if (idx < 33024){
    int j = idx - 32768;
    const void* s = (j < 128) ? b1 : b2;
    int i2 = j & 127;
    bb[j] = f ? f2bf(((const float*)s)[i2]) : ((const uint16_t*)s)[i2];
  }
}

__device__ __forceinline__ short8 ldcvt(const float* __restrict__ p){
  floatx4 u = ((const floatx4*)p)[0], v = ((const floatx4*)p)[1];
  short8 r;
  r[0] = (short)f2bf(u.x); r[1] = (short)f2bf(u.y);
  r[2] = (short)f2bf(u.z); r[3] = (short)f2bf(u.w);
  r[4] = (short)f2bf(v.x); r[5] = (short)f2bf(v.y);
  r[6] = (short)f2bf(v.z); r[7] = (short)f2bf(v.w);
  return r;
}

// ---------------- GEMM: H = X * W (bf16 MFMA 16x16x32), optional f32 input ----
__global__ __launch_bounds__(256) void k_gemm(const void* __restrict__ X,
                                              const uint16_t* __restrict__ WT,
                                              uint16_t* __restrict__ H,
                                              const int* __restrict__ flag,
                                              int xf32){
  __shared__ uint16_t lwt[128 * 136];   // +8 shorts pad -> 2-way bank alias (free)
  int t = threadIdx.x;
  const uint32_t* wt32 = (const uint32_t*)WT;
  #pragma unroll
  for (int i = 0; i < 32; i++){
    int uidx = t + 256 * i;
    uint32_t w2 = wt32[uidx];
    int el = uidx * 2;
    int c = el >> 7, k = el & 127;
    *(uint32_t*)&lwt[c * 136 + k] = w2;
  }
  __syncthreads();

  int wave = t >> 6, lane = t & 63;
  int m = lane & 15, q = lane >> 4;
  int rowbase = blockIdx.x * 64 + wave * 16;
  int ar = rowbase + m;
  if (ar >= NN) ar = 0;
  short8 a0, a1, a2, a3;
  if (xf32 && flag[0]){
    const float* xr = (const float*)X + (size_t)ar * DD;
    a0 = ldcvt(xr + q * 8);        a1 = ldcvt(xr + (q + 4) * 8);
    a2 = ldcvt(xr + (q + 8) * 8);  a3 = ldcvt(xr + (q + 12) * 8);
  } else {
    const short8* xrow = (const short8*)((const uint16_t*)X + (size_t)ar * DD);
    a0 = xrow[q]; a1 = xrow[q + 4]; a2 = xrow[q + 8]; a3 = xrow[q + 12];
  }

  #pragma unroll
  for (int nt = 0; nt < 8; nt++){
    int c = nt * 16 + m;
    const uint16_t* bp = &lwt[c * 136 + q * 8];
    floatx4 acc = {0.f, 0.f, 0.f, 0.f};
    acc = __builtin_amdgcn_mfma_f32_16x16x32_bf16(a0, *(const short8*)(bp +  0), acc, 0, 0, 0);
    acc = __builtin_amdgcn_mfma_f32_16x16x32_bf16(a1, *(const short8*)(bp + 32), acc, 0, 0, 0);
    acc = __builtin_amdgcn_mfma_f32_16x16x32_bf16(a2, *(const short8*)(bp + 64), acc, 0, 0, 0);
    acc = __builtin_amdgcn_mfma_f32_16x16x32_bf16(a3, *(const short8*)(bp + 96), acc, 0, 0, 0);
    #pragma unroll
    for (int r = 0; r < 4; r++){
      int row = rowbase + q * 4 + r;
      if (row < NN) H[(size_t)row * DD + c] = f2bf(acc[r]);
    }
  }
}

#define FMA8(VA, CF)                                                     \
  acc[0] = fmaf(__uint_as_float(VA.x << 16),         CF, acc[0]);        \
  acc[1] = fmaf(__uint_as_float(VA.x & 0xffff0000u), CF, acc[1]);        \
  acc[2] = fmaf(__uint_as_float(VA.y << 16),         CF, acc[2]);        \
  acc[3] = fmaf(__uint_as_float(VA.y & 0xffff0000u), CF, acc[3]);        \
  acc[4] = fmaf(__uint_as_float(VA.z << 16),         CF, acc[4]);        \
  acc[5] = fmaf(__uint_as_float(VA.z & 0xffff0000u), CF, acc[5]);        \
  acc[6] = fmaf(__uint_as_float(VA.w << 16),         CF, acc[6]);        \
  acc[7] = fmaf(__uint_as_float(VA.w & 0xffff0000u), CF, acc[7]);

// ---------------- aggregation: 16 nodes/wave, precomputed records -------------
// Record stream (self-loop included) is contiguous per wave's node range.
// lane = grp*16 + sl: grp = edge-in-chunk(4), sl = dim-slice (8 dims, 16 B).
// Double-buffered LDS stage + next-node register prefetch + 2-deep h pipeline.
__global__ __launch_bounds__(256) void k_agg(const uint16_t* __restrict__ H,
                                             const int* __restrict__ prow,
                                             const int2* __restrict__ pairs2,
                                             const uint16_t* __restrict__ bias,
                                             void* __restrict__ OUT,
                                             const int* __restrict__ flag,
                                             int is_final){
  __shared__ int2 ebuf[4][2][72];   // [wave][buf][64 + 8 pad]
  int wave = threadIdx.x >> 6, lane = threadIdx.x & 63;
  int grp = lane >> 4, sl = lane & 15;
  if (lane < 8){
    ebuf[wave][0][64 + lane] = make_int2(0, 0);
    ebuf[wave][1][64 + lane] = make_int2(0, 0);
  }
  int n0 = (blockIdx.x * 4 + wave) * 16;
  if (n0 >= NN) return;
  int n1 = min(n0 + 16, NN);
  int pnxt = prow[n0 + 1];
  int beg = prow[n0], cnt = pnxt - beg;
  int2 rec = (lane < cnt) ? pairs2[beg + lane] : make_int2(0, 0);
  int buf = 0;
  int wrf32 = is_final && flag[0];
  uint32x4 bv = ((const uint32x4*)bias)[sl];

  for (int n = n0; n < n1; n++){
    ebuf[wave][buf][lane] = rec;
    // prefetch next node's records (in flight during this node's crunch)
    int beg2 = 0, cnt2 = 0;
    if (n + 1 < n1){
      int pn2 = prow[n + 2];
      beg2 = pnxt; cnt2 = pn2 - pnxt;
      pnxt = pn2;
    }
    int2 rec2 = (lane < cnt2) ? pairs2[beg2 + lane] : make_int2(0, 0);

    float acc[8] = {0.f,0.f,0.f,0.f,0.f,0.f,0.f,0.f};
    int bcnt = min(cnt, 64);
    int chunks = (bcnt + 3) >> 2;
    int2 ea = ebuf[wave][buf][grp];
    uint32x4 va = *(const uint32x4*)(H + (size_t)ea.x * DD + sl * 8);
    for (int c = 0; c < chunks; c++){
      int2 eb = ebuf[wave][buf][c * 4 + 4 + grp];
      uint32x4 vb = *(const uint32x4*)(H + (size_t)eb.x * DD + sl * 8);
      float cf = __int_as_float(ea.y);
      FMA8(va, cf)
      ea = eb; va = vb;
    }
    for (int done = 64; done < cnt; done += 64){   // overflow: deg+1 > 64 (never hit here)
      int rb = min(cnt - done, 64);
      ebuf[wave][buf][lane] = (lane < rb) ? pairs2[beg + done + lane] : make_int2(0, 0);
      int ch2 = (rb + 3) >> 2;
      ea = ebuf[wave][buf][grp];
      va = *(const uint32x4*)(H + (size_t)ea.x * DD + sl * 8);
      for (int c = 0; c < ch2; c++){
        int2 eb = ebuf[wave][buf][c * 4 + 4 + grp];
        uint32x4 vb = *(const uint32x4*)(H + (size_t)eb.x * DD + sl * 8);
        float cf = __int_as_float(ea.y);
        FMA8(va, cf)
        ea = eb; va = vb;
      }
    }
    #pragma unroll
    for (int j = 0; j < 8; j++){
      acc[j] += __shfl_xor(acc[j], 16, 64);
      acc[j] += __shfl_xor(acc[j], 32, 64);
    }
    float o0 = lrelu(acc[0] + __uint_as_float(bv.x << 16));
    float o1 = lrelu(acc[1] + __uint_as_float(bv.x & 0xffff0000u));
    float o2 = lrelu(acc[2] + __uint_as_float(bv.y << 16));
    float o3 = lrelu(acc[3] + __uint_as_float(bv.y & 0xffff0000u));
    float o4 = lrelu(acc[4] + __uint_as_float(bv.z << 16));
    float o5 = lrelu(acc[5] + __uint_as_float(bv.z & 0xffff0000u));
    float o6 = lrelu(acc[6] + __uint_as_float(bv.w << 16));
    float o7 = lrelu(acc[7] + __uint_as_float(bv.w & 0xffff0000u));
    if (wrf32){
      float* orow = (float*)OUT + (size_t)n * DD + sl * 8;
      if (lane < 16){ floatx4 vv = {o0, o1, o2, o3}; ((floatx4*)orow)[0] = vv; }
      else if (lane < 32){ floatx4 vv = {o4, o5, o6, o7}; ((floatx4*)orow)[1] = vv; }
    } else if (lane < 16){
      uint32x4 pv;
      pv.x = (uint32_t)f2bf(o0) | ((uint32_t)f2bf(o1) << 16);
      pv.y = (uint32_t)f2bf(o2) | ((uint32_t)f2bf(o3) << 16);
      pv.z = (uint32_t)f2bf(o4) | ((uint32_t)f2bf(o5) << 16);
      pv.w = (uint32_t)f2bf(o6) | ((uint32_t)f2bf(o7) << 16);
      *(uint32x4*)((uint16_t*)OUT + (size_t)n * DD + sl * 8) = pv;
    }
    buf ^= 1; rec = rec2; beg = beg2; cnt = cnt2;
  }
}

extern "C" void kernel_launch(void* const* d_in, const int* in_sizes, int n_in,
                              void* d_out, int out_size, void* d_ws, size_t ws_size,
                              hipStream_t stream){
  const void* x  = d_in[0];
  const void* W1 = d_in[1];
  const void* b1 = d_in[2];
  const void* W2 = d_in[3];
  const void* b2 = d_in[4];
  const int* ei   = (const int*)d_in[5];
  const int* esrc = ei;
  const int* edst = ei + NE;

  char* ws = (char*)d_ws;
  float*    dis        = (float*)(ws + 0);                     // 400,000 B
  int*      prow       = (int*)(ws + 512ull * 1024);           // 400,004 B
  int*      flag       = (int*)(ws + 960ull * 1024);           // 4 B
  uint16_t* WT1        = (uint16_t*)(ws + 964ull * 1024);      // 32 KiB
  uint16_t* WT2        = (uint16_t*)(ws + 996ull * 1024);      // 32 KiB
  uint16_t* bb         = (uint16_t*)(ws + 1028ull * 1024);     // 512 B
  int*      ghist      = (int*)(ws + 1032ull * 1024);          // 306,544 B
  int*      btotal     = (int*)(ws + 1344ull * 1024);          // 784 B
  int*      bucketbase = (int*)(ws + 1348ull * 1024);          // 788 B
  int2*     pairs2     = (int2*)(ws + 2048ull * 1024);         // 13.6 MB
  uint64_t* pairs      = (uint64_t*)(ws + 16384ull * 1024);    // 12.8 MB (dead pre-gemm1)
  uint16_t* hA         = (uint16_t*)(ws + 16384ull * 1024);    // 25.6 MB (aliases pairs)
  uint16_t* hB         = (uint16_t*)d_out;                     // scratch; gemm2 reads before agg2 writes

  k_detect<<<1, 64, 0, stream>>>((const uint32_t*)x, flag);
  k_hist  <<<NBLK1, 256, 0, stream>>>(edst, ghist);
  k_bscan <<<NB, 512, 0, stream>>>(ghist, btotal);
  k_bscan2<<<1, 256, 0, stream>>>(btotal, bucketbase);
  k_scatter<<<NBLK1, 256, 0, stream>>>(esrc, edst, ghist, bucketbase, pairs);
  k_bsort <<<NB, 512, 0, stream>>>(pairs, bucketbase, pairs2, prow, dis);
  k_prep2 <<<(NR + 255) / 256, 256, 0, stream>>>(pairs2, dis);
  k_wb    <<<129, 256, 0, stream>>>(W1, W2, b1, b2, WT1, WT2, bb, flag);

  k_gemm<<<(NN + 63) / 64, 256, 0, stream>>>(x, WT1, hA, flag, 1);
  k_agg <<<(NN + 63) / 64, 256, 0, stream>>>(hA, prow, pairs2, bb, hB, flag, 0);
  k_gemm<<<(NN + 63) / 64, 256, 0, stream>>>(hB, WT2, hA, flag, 0);
  k_agg <<<(NN + 63) / 64, 256, 0, stream>>>(hA, prow, pairs2, bb + 128, d_out, flag, 1);
}

// Round 6
// 321.392 us; speedup vs baseline: 1.0955x; 1.0955x over previous
//
#include <hip/hip_runtime.h>
#include <hip/hip_bf16.h>
#include <stdint.h>

#define NN 100000
#define NE 1600000
#define NR (NE + NN)   // records incl. self-loops
#define DD 128
#define NEG 0.01f
#define NB 196        // coarse buckets of 512 nodes (dst>>9)
#define EPB 4096      // edges per block in hist/scatter
#define NBLK1 391     // ceil(NE/EPB)

typedef __attribute__((ext_vector_type(8))) short short8;
typedef __attribute__((ext_vector_type(4))) float floatx4;
typedef __attribute__((ext_vector_type(4))) uint32_t uint32x4;

__device__ __forceinline__ uint16_t f2bf(float f){
  uint32_t i = __float_as_uint(f);
  return (uint16_t)((i + 0x7FFFu + ((i >> 16) & 1u)) >> 16);  // RNE
}
__device__ __forceinline__ float lrelu(float x){ return fmaxf(x, NEG * x); }

// ---------------- dtype detect: are float tensors f32 or bf16? ----------------
__global__ void k_detect(const uint32_t* __restrict__ xw, int* __restrict__ flag){
  int lane = threadIdx.x;
  uint32_t w = xw[lane];
  uint32_t e = (w >> 7) & 0xFFu;
  int plaus = (e >= 100u && e <= 134u) ? 1 : 0;
  unsigned long long b = __ballot(plaus);
  if (lane == 0) flag[0] = (__popcll(b) >= 48) ? 0 : 1;
}

// ---------------- CSR build: deterministic two-level counting sort ------------
__global__ __launch_bounds__(256) void k_hist(const int* __restrict__ dst,
                                              int* __restrict__ ghist){
  __shared__ int lh[NB];
  int t = threadIdx.x, b = blockIdx.x;
  if (t < NB) lh[t] = 0;
  __syncthreads();
  #pragma unroll
  for (int i = 0; i < 16; i++){
    int e = b * EPB + i * 256 + t;
    if (e < NE) atomicAdd(&lh[dst[e] >> 9], 1);
  }
  __syncthreads();
  if (t < NB) ghist[t * NBLK1 + b] = lh[t];
}

__global__ __launch_bounds__(512) void k_bscan(int* __restrict__ ghist,
                                               int* __restrict__ btotal){
  __shared__ int sm[512];
  int t = threadIdx.x, bkt = blockIdx.x;
  int v = (t < NBLK1) ? ghist[bkt * NBLK1 + t] : 0;
  sm[t] = v;
  __syncthreads();
  for (int s = 1; s < 512; s <<= 1){
    int add = (t >= s) ? sm[t - s] : 0;
    __syncthreads();
    sm[t] += add;
    __syncthreads();
  }
  if (t < NBLK1) ghist[bkt * NBLK1 + t] = sm[t] - v;   // exclusive
  if (t == 0) btotal[bkt] = sm[511];
}

__global__ __launch_bounds__(256) void k_bscan2(const int* __restrict__ btotal,
                                                int* __restrict__ bucketbase){
  __shared__ int sm[256];
  int t = threadIdx.x;
  int v = (t < NB) ? btotal[t] : 0;
  sm[t] = v;
  __syncthreads();
  for (int s = 1; s < 256; s <<= 1){
    int add = (t >= s) ? sm[t - s] : 0;
    __syncthreads();
    sm[t] += add;
    __syncthreads();
  }
  if (t < NB) bucketbase[t] = sm[t] - v;
  if (t == 0) bucketbase[NB] = sm[255];   // == NE
}

__global__ __launch_bounds__(256) void k_scatter(const int* __restrict__ src,
                                                 const int* __restrict__ dst,
                                                 const int* __restrict__ ghist,
                                                 const int* __restrict__ bucketbase,
                                                 uint64_t* __restrict__ pairs){
  __shared__ int lcur[NB];
  int t = threadIdx.x, b = blockIdx.x;
  if (t < NB) lcur[t] = bucketbase[t] + ghist[t * NBLK1 + b];
  __syncthreads();
  #pragma unroll
  for (int i = 0; i < 16; i++){
    int e = b * EPB + i * 256 + t;
    if (e < NE){
      int s = src[e], d = dst[e];
      int pos = atomicAdd(&lcur[d >> 9], 1);
      pairs[pos] = ((uint64_t)(uint32_t)d << 32) | (uint32_t)s;
    }
  }
}

// Per-bucket fine sort -> record stream pairs2 {src, partial coef}, prowstart, dis.
// Records per node: [self {n, dn}] then [edges {src, dn}]; k_prep2 multiplies
// every record's coef by dis[src] afterwards (self becomes dn^2).
__global__ __launch_bounds__(512) void k_bsort(const uint64_t* __restrict__ pairs,
                                               const int* __restrict__ bucketbase,
                                               int2* __restrict__ pairs2,
                                               int* __restrict__ prowstart,
                                               float* __restrict__ dis){
  __shared__ int lcnt[512], lofs[512], sm[512];
  __shared__ float sdn[512];
  int t = threadIdx.x, bkt = blockIdx.x;
  int n0 = bkt << 9;
  int beg = bucketbase[bkt], end = bucketbase[bkt + 1];
  int begS = beg + n0;                   // self-inclusive base (n0 nodes precede)
  lcnt[t] = 0;
  __syncthreads();
  for (int i = beg + t; i < end; i += 512){
    int d = (int)(pairs[i] >> 32);
    atomicAdd(&lcnt[d - n0], 1);
  }
  __syncthreads();
  int n = n0 + t;
  int inb = (n < NN) ? 1 : 0;
  int v = lcnt[t] + inb;                 // +1 slot for self record
  sm[t] = v;
  __syncthreads();
  for (int s = 1; s < 512; s <<= 1){
    int add = (t >= s) ? sm[t - s] : 0;
    __syncthreads();
    sm[t] += add;
    __syncthreads();
  }
  int excl = sm[t] - v;
  float dn = rsqrtf((float)(lcnt[t] + 1));
  lofs[t] = excl + 1;                    // first edge slot (after self)
  sdn[t] = dn;
  if (inb){
    prowstart[n] = begS + excl;
    dis[n] = dn;
    pairs2[begS + excl] = make_int2(n, __float_as_int(dn));   // partial self
  }
  if (bkt == 0 && t == 0) prowstart[NN] = NR;
  __syncthreads();
  for (int i = beg + t; i < end; i += 512){
    uint64_t u = pairs[i];
    int d = (int)(u >> 32);
    int p = atomicAdd(&lofs[d - n0], 1);
    pairs2[begS + p] = make_int2((int)(uint32_t)u, __float_as_int(sdn[d - n0]));
  }
}

// Finalize coefs: rec.coef *= dis[rec.src]  (edge-parallel, coalesced)
__global__ void k_prep2(int2* __restrict__ pairs2, const float* __restrict__ dis){
  int i = blockIdx.x * 256 + threadIdx.x;
  if (i < NR){
    int2 r = pairs2[i];
    r.y = __float_as_int(__int_as_float(r.y) * dis[r.x]);
    pairs2[i] = r;
  }
}

// ---------------- weights transpose + bias pack (merged, +dtype convert) ------
__global__ void k_wb(const void* __restrict__ W1, const void* __restrict__ W2,
                     const void* __restrict__ b1, const void* __restrict__ b2,
                     uint16_t* __restrict__ WT1, uint16_t* __restrict__ WT2,
                     uint16_t* __restrict__ bb, const int* __restrict__ flag){
  int idx = blockIdx.x * 256 + threadIdx.x;   // 129 blocks -> 33024
  int f = flag[0];
  if (idx < 16384){
    int c = idx >> 7, k = idx & 127;
    WT1[idx] = f ? f2bf(((const float*)W1)[k * DD + c])
                 : ((const uint16_t*)W1)[k * DD + c];
  } else if (idx < 32768){
    int j = idx - 16384;
    int c = j >> 7, k = j & 127;
    WT2[j] = f ? f2bf(((const float*)W2)[k * DD + c])
               : ((const uint16_t*)W2)[k * DD + c];
  } else if (idx < 33024){
    int j = idx - 32768;
    const void* s = (j < 128) ? b1 : b2;
    int i2 = j & 127;
    bb[j] = f ? f2bf(((const float*)s)[i2]) : ((const uint16_t*)s)[i2];
  }
}

__device__ __forceinline__ short8 ldcvt(const float* __restrict__ p){
  floatx4 u = ((const floatx4*)p)[0], v = ((const floatx4*)p)[1];
  short8 r;
  r[0] = (short)f2bf(u.x); r[1] = (short)f2bf(u.y);
  r[2] = (short)f2bf(u.z); r[3] = (short)f2bf(u.w);
  r[4] = (short)f2bf(v.x); r[5] = (short)f2bf(v.y);
  r[6] = (short)f2bf(v.z); r[7] = (short)f2bf(v.w);
  return r;
}

// ---------------- GEMM: H = X * W (bf16 MFMA 16x16x32), optional f32 input ----
__global__ __launch_bounds__(256) void k_gemm(const void* __restrict__ X,
                                              const uint16_t* __restrict__ WT,
                                              uint16_t* __restrict__ H,
                                              const int* __restrict__ flag,
                                              int xf32){
  __shared__ uint16_t lwt[128 * 136];   // +8 shorts pad -> 2-way bank alias (free)
  int t = threadIdx.x;
  const uint32_t* wt32 = (const uint32_t*)WT;
  #pragma unroll
  for (int i = 0; i < 32; i++){
    int uidx = t + 256 * i;
    uint32_t w2 = wt32[uidx];
    int el = uidx * 2;
    int c = el >> 7, k = el & 127;
    *(uint32_t*)&lwt[c * 136 + k] = w2;
  }
  __syncthreads();

  int wave = t >> 6, lane = t & 63;
  int m = lane & 15, q = lane >> 4;
  int rowbase = blockIdx.x * 64 + wave * 16;
  int ar = rowbase + m;
  if (ar >= NN) ar = 0;
  short8 a0, a1, a2, a3;
  if (xf32 && flag[0]){
    const float* xr = (const float*)X + (size_t)ar * DD;
    a0 = ldcvt(xr + q * 8);        a1 = ldcvt(xr + (q + 4) * 8);
    a2 = ldcvt(xr + (q + 8) * 8);  a3 = ldcvt(xr + (q + 12) * 8);
  } else {
    const short8* xrow = (const short8*)((const uint16_t*)X + (size_t)ar * DD);
    a0 = xrow[q]; a1 = xrow[q + 4]; a2 = xrow[q + 8]; a3 = xrow[q + 12];
  }

  #pragma unroll
  for (int nt = 0; nt < 8; nt++){
    int c = nt * 16 + m;
    const uint16_t* bp = &lwt[c * 136 + q * 8];
    floatx4 acc = {0.f, 0.f, 0.f, 0.f};
    acc = __builtin_amdgcn_mfma_f32_16x16x32_bf16(a0, *(const short8*)(bp +  0), acc, 0, 0, 0);
    acc = __builtin_amdgcn_mfma_f32_16x16x32_bf16(a1, *(const short8*)(bp + 32), acc, 0, 0, 0);
    acc = __builtin_amdgcn_mfma_f32_16x16x32_bf16(a2, *(const short8*)(bp + 64), acc, 0, 0, 0);
    acc = __builtin_amdgcn_mfma_f32_16x16x32_bf16(a3, *(const short8*)(bp + 96), acc, 0, 0, 0);
    #pragma unroll
    for (int r = 0; r < 4; r++){
      int row = rowbase + q * 4 + r;
      if (row < NN) H[(size_t)row * DD + c] = f2bf(acc[r]);
    }
  }
}

#define FMA8(VA, CF)                                                     \
  acc[0] = fmaf(__uint_as_float(VA.x << 16),         CF, acc[0]);        \
  acc[1] = fmaf(__uint_as_float(VA.x & 0xffff0000u), CF, acc[1]);        \
  acc[2] = fmaf(__uint_as_float(VA.y << 16),         CF, acc[2]);        \
  acc[3] = fmaf(__uint_as_float(VA.y & 0xffff0000u), CF, acc[3]);        \
  acc[4] = fmaf(__uint_as_float(VA.z << 16),         CF, acc[4]);        \
  acc[5] = fmaf(__uint_as_float(VA.z & 0xffff0000u), CF, acc[5]);        \
  acc[6] = fmaf(__uint_as_float(VA.w << 16),         CF, acc[6]);        \
  acc[7] = fmaf(__uint_as_float(VA.w & 0xffff0000u), CF, acc[7]);

// ---------------- aggregation: ONE node/wave (max TLP), precomputed records ---
// Records include self-loop with coef dn^2 -> no separate self term.
// lane = grp*16 + sl: grp = edge-in-chunk(4), sl = dim-slice (8 dims, 16 B).
// Per 64-record batch: one 8 B/lane load -> LDS stage -> 2-deep h pipeline.
__global__ __launch_bounds__(256) void k_agg(const uint16_t* __restrict__ H,
                                             const int* __restrict__ prow,
                                             const int2* __restrict__ pairs2,
                                             const uint16_t* __restrict__ bias,
                                             void* __restrict__ OUT,
                                             const int* __restrict__ flag,
                                             int is_final){
  __shared__ int2 ebuf[4][68];   // [wave][64 + 4 zero-pad]
  int wave = threadIdx.x >> 6, lane = threadIdx.x & 63;
  int grp = lane >> 4, sl = lane & 15;
  if (lane < 4) ebuf[wave][64 + lane] = make_int2(0, 0);
  int n = blockIdx.x * 4 + wave;
  if (n >= NN) return;
  int beg = prow[n], end = prow[n + 1];

  float acc[8] = {0.f,0.f,0.f,0.f,0.f,0.f,0.f,0.f};
  for (int j0 = beg; j0 < end; j0 += 64){
    int cnt = min(64, end - j0);
    int2 r = (lane < cnt) ? pairs2[j0 + lane] : make_int2(0, 0);
    ebuf[wave][lane] = r;
    int chunks = (cnt + 3) >> 2;
    int2 ea = ebuf[wave][grp];
    uint32x4 va = *(const uint32x4*)(H + (size_t)ea.x * DD + sl * 8);
    for (int c = 0; c < chunks; c++){
      int2 eb = ebuf[wave][c * 4 + 4 + grp];
      uint32x4 vb = *(const uint32x4*)(H + (size_t)eb.x * DD + sl * 8);
      float cf = __int_as_float(ea.y);
      FMA8(va, cf)
      ea = eb; va = vb;
    }
  }
  #pragma unroll
  for (int j = 0; j < 8; j++){
    acc[j] += __shfl_xor(acc[j], 16, 64);
    acc[j] += __shfl_xor(acc[j], 32, 64);
  }
  uint32x4 bv = ((const uint32x4*)bias)[sl];
  float o0 = lrelu(acc[0] + __uint_as_float(bv.x << 16));
  float o1 = lrelu(acc[1] + __uint_as_float(bv.x & 0xffff0000u));
  float o2 = lrelu(acc[2] + __uint_as_float(bv.y << 16));
  float o3 = lrelu(acc[3] + __uint_as_float(bv.y & 0xffff0000u));
  float o4 = lrelu(acc[4] + __uint_as_float(bv.z << 16));
  float o5 = lrelu(acc[5] + __uint_as_float(bv.z & 0xffff0000u));
  float o6 = lrelu(acc[6] + __uint_as_float(bv.w << 16));
  float o7 = lrelu(acc[7] + __uint_as_float(bv.w & 0xffff0000u));
  if (is_final && flag[0]){
    float* orow = (float*)OUT + (size_t)n * DD + sl * 8;
    if (lane < 16){ floatx4 vv = {o0, o1, o2, o3}; ((floatx4*)orow)[0] = vv; }
    else if (lane < 32){ floatx4 vv = {o4, o5, o6, o7}; ((floatx4*)orow)[1] = vv; }
  } else if (lane < 16){
    uint32x4 pv;
    pv.x = (uint32_t)f2bf(o0) | ((uint32_t)f2bf(o1) << 16);
    pv.y = (uint32_t)f2bf(o2) | ((uint32_t)f2bf(o3) << 16);
    pv.z = (uint32_t)f2bf(o4) | ((uint32_t)f2bf(o5) << 16);
    pv.w = (uint32_t)f2bf(o6) | ((uint32_t)f2bf(o7) << 16);
    *(uint32x4*)((uint16_t*)OUT + (size_t)n * DD + sl * 8) = pv;
  }
}

extern "C" void kernel_launch(void* const* d_in, const int* in_sizes, int n_in,
                              void* d_out, int out_size, void* d_ws, size_t ws_size,
                              hipStream_t stream){
  const void* x  = d_in[0];
  const void* W1 = d_in[1];
  const void* b1 = d_in[2];
  const void* W2 = d_in[3];
  const void* b2 = d_in[4];
  const int* ei   = (const int*)d_in[5];
  const int* esrc = ei;
  const int* edst = ei + NE;

  char* ws = (char*)d_ws;
  float*    dis        = (float*)(ws + 0);                     // 400,000 B
  int*      prow       = (int*)(ws + 512ull * 1024);           // 400,004 B
  int*      flag       = (int*)(ws + 960ull * 1024);           // 4 B
  uint16_t* WT1        = (uint16_t*)(ws + 964ull * 1024);      // 32 KiB
  uint16_t* WT2        = (uint16_t*)(ws + 996ull * 1024);      // 32 KiB
  uint16_t* bb         = (uint16_t*)(ws + 1028ull * 1024);     // 512 B
  int*      ghist      = (int*)(ws + 1032ull * 1024);          // 306,544 B
  int*      btotal     = (int*)(ws + 1344ull * 1024);          // 784 B
  int*      bucketbase = (int*)(ws + 1348ull * 1024);          // 788 B
  int2*     pairs2     = (int2*)(ws + 2048ull * 1024);         // 13.6 MB
  uint64_t* pairs      = (uint64_t*)(ws + 16384ull * 1024);    // 12.8 MB (dead pre-gemm1)
  uint16_t* hA         = (uint16_t*)(ws + 16384ull * 1024);    // 25.6 MB (aliases pairs)
  uint16_t* hB         = (uint16_t*)d_out;                     // scratch; gemm2 reads before agg2 writes

  k_detect<<<1, 64, 0, stream>>>((const uint32_t*)x, flag);
  k_hist  <<<NBLK1, 256, 0, stream>>>(edst, ghist);
  k_bscan <<<NB, 512, 0, stream>>>(ghist, btotal);
  k_bscan2<<<1, 256, 0, stream>>>(btotal, bucketbase);
  k_scatter<<<NBLK1, 256, 0, stream>>>(esrc, edst, ghist, bucketbase, pairs);
  k_bsort <<<NB, 512, 0, stream>>>(pairs, bucketbase, pairs2, prow, dis);
  k_prep2 <<<(NR + 255) / 256, 256, 0, stream>>>(pairs2, dis);
  k_wb    <<<129, 256, 0, stream>>>(W1, W2, b1, b2, WT1, WT2, bb, flag);

  k_gemm<<<(NN + 63) / 64, 256, 0, stream>>>(x, WT1, hA, flag, 1);
  k_agg <<<NN / 4, 256, 0, stream>>>(hA, prow, pairs2, bb, hB, flag, 0);
  k_gemm<<<(NN + 63) / 64, 256, 0, stream>>>(hB, WT2, hA, flag, 0);
  k_agg <<<NN / 4, 256, 0, stream>>>(hA, prow, pairs2, bb + 128, d_out, flag, 1);
}